// Round 6
// baseline (1572.121 us; speedup 1.0000x reference)
//
#include <hip/hip_runtime.h>

// =====================================================================
// DecoderLayer: selfMHA -> LN -> crossMHA -> LN -> 32xLSTM(pipelined)
//               -> pointwise conv -> LN
// Round 6: MFMA persistent LSTM. One wave = one (layer, 16-batch) chain;
//          gate rows permuted r=4u+g so MFMA C/D layout makes elementwise
//          lane-local; ring in B-frag layout read directly (no staging);
//          zero barriers. GEMM/attention unchanged from R5.
// =====================================================================

#define EPS_LN 1e-5f

typedef _Float16 h8v __attribute__((ext_vector_type(8)));
typedef float    f4v __attribute__((ext_vector_type(4)));

// ---------------- fused weight prep: 8 transposes + 1 straight cvt -------
struct WPtrs { const float* p[9]; };

__global__ __launch_bounds__(256)
void prep_weights(WPtrs w, _Float16* __restrict__ dst) {
  __shared__ float tile[32][33];
  const int z = blockIdx.z;
  const int tx = threadIdx.x & 31, ty = threadIdx.x >> 5;
  const int bx = blockIdx.x, by = blockIdx.y;
  const float* in = w.p[z];
  _Float16* outp = dst + (size_t)z * 262144;
  if (z < 8) {
#pragma unroll
    for (int i = 0; i < 4; i++)
      tile[ty + i * 8][tx] = in[(size_t)(by * 32 + ty + i * 8) * 512 + bx * 32 + tx];
    __syncthreads();
#pragma unroll
    for (int i = 0; i < 4; i++)
      outp[(size_t)(bx * 32 + ty + i * 8) * 512 + by * 32 + tx] = (_Float16)tile[tx][ty + i * 8];
  } else {
#pragma unroll
    for (int i = 0; i < 4; i++) {
      size_t off = (size_t)(by * 32 + ty + i * 8) * 512 + bx * 32 + tx;
      outp[off] = (_Float16)in[off];
    }
  }
}

// ---------------- f16 MFMA GEMM, fp32 A staged+converted in LDS ----------
__global__ __launch_bounds__(256)
void gemm3(const float* __restrict__ A,
           const _Float16* __restrict__ BT0, const _Float16* __restrict__ BT1,
           const _Float16* __restrict__ BT2,
           const float* __restrict__ bias0, const float* __restrict__ bias1,
           const float* __restrict__ bias2,
           float* __restrict__ C0, float* __restrict__ C1, float* __restrict__ C2,
           int M) {
  __shared__ _Float16 Asld[64 * 40];
  __shared__ _Float16 Bsld[64 * 40];
  const int t = threadIdx.x;
  const int which = blockIdx.x >> 3;
  const int n0 = (blockIdx.x & 7) * 64;
  const int m0 = blockIdx.y * 64;
  const _Float16* BT = (which == 0) ? BT0 : (which == 1) ? BT1 : BT2;
  const float* bias  = (which == 0) ? bias0 : (which == 1) ? bias1 : bias2;
  float* C           = (which == 0) ? C0 : (which == 1) ? C1 : C2;

  const int r = t >> 2, q = t & 3;
  const int w = t >> 6;
  const int lane = t & 63;
  const int lm = lane & 15, q8 = lane >> 4;

  f4v acc[4] = {};
  for (int k0 = 0; k0 < 512; k0 += 32) {
    __syncthreads();
    float4 f0 = *(const float4*)&A[(size_t)(m0 + r) * 512 + k0 + q * 8];
    float4 f1 = *(const float4*)&A[(size_t)(m0 + r) * 512 + k0 + q * 8 + 4];
    h8v hvv = {(_Float16)f0.x, (_Float16)f0.y, (_Float16)f0.z, (_Float16)f0.w,
               (_Float16)f1.x, (_Float16)f1.y, (_Float16)f1.z, (_Float16)f1.w};
    *(h8v*)&Asld[r * 40 + q * 8] = hvv;
    *(uint4*)&Bsld[r * 40 + q * 8] = *(const uint4*)&BT[(size_t)(n0 + r) * 512 + k0 + q * 8];
    __syncthreads();
    h8v a = *(const h8v*)&Asld[(w * 16 + lm) * 40 + q8 * 8];
#pragma unroll
    for (int nt = 0; nt < 4; nt++) {
      h8v b = *(const h8v*)&Bsld[(nt * 16 + lm) * 40 + q8 * 8];
      acc[nt] = __builtin_amdgcn_mfma_f32_16x16x32_f16(a, b, acc[nt], 0, 0, 0);
    }
  }
#pragma unroll
  for (int nt = 0; nt < 4; nt++) {
    int gn = n0 + nt * 16 + lm;
    float bv = bias[gn];
#pragma unroll
    for (int rg = 0; rg < 4; rg++) {
      int gm = m0 + w * 16 + q8 * 4 + rg;
      C[(size_t)gm * 512 + gn] = acc[nt][rg] + bv;
    }
  }
}

// ---------------- attention: scores then softmax+PV, per (b,h) -----------
template <int S>
__global__ __launch_bounds__(256)
void attn_scores(const float* __restrict__ Q, const float* __restrict__ K,
                 float* __restrict__ P) {
  __shared__ float Qs[25][64];
  __shared__ float Ks[S][65];
  const int h = blockIdx.x, b = blockIdx.y, t = threadIdx.x;
  for (int idx = t; idx < 25 * 64; idx += 256) {
    int l = idx >> 6, e = idx & 63;
    Qs[l][e] = Q[(b * 25 + l) * 512 + h * 64 + e];
  }
  for (int idx = t; idx < S * 64; idx += 256) {
    int s = idx >> 6, e = idx & 63;
    Ks[s][e] = K[(b * S + s) * 512 + h * 64 + e];
  }
  __syncthreads();
  float* Pb = P + (size_t)(b * 8 + h) * 25 * S;
  for (int idx = t; idx < 25 * S; idx += 256) {
    int l = idx / S, s = idx % S;
    float acc = 0.f;
#pragma unroll
    for (int e = 0; e < 64; e++) acc += Qs[l][e] * Ks[s][e];
    Pb[idx] = acc * 0.125f;
  }
}

template <int S>
__global__ __launch_bounds__(256)
void attn_out(const float* __restrict__ P, const float* __restrict__ V,
              float* __restrict__ O) {
  __shared__ float Ps[25][S];
  __shared__ float Vs[S][64];
  const int h = blockIdx.x, b = blockIdx.y, t = threadIdx.x;
  const float* Pb = P + (size_t)(b * 8 + h) * 25 * S;
  for (int idx = t; idx < 25 * S; idx += 256) Ps[idx / S][idx % S] = Pb[idx];
  for (int idx = t; idx < S * 64; idx += 256) {
    int s = idx >> 6, e = idx & 63;
    Vs[s][e] = V[(b * S + s) * 512 + h * 64 + e];
  }
  __syncthreads();
  if (t < 25) {
    float mx = -1e30f;
    for (int s = 0; s < S; s++) mx = fmaxf(mx, Ps[t][s]);
    float sum = 0.f;
    for (int s = 0; s < S; s++) { float p = __expf(Ps[t][s] - mx); Ps[t][s] = p; sum += p; }
    float r = 1.f / sum;
    for (int s = 0; s < S; s++) Ps[t][s] *= r;
  }
  __syncthreads();
  for (int idx = t; idx < 25 * 64; idx += 256) {
    int l = idx >> 6, e = idx & 63;
    float acc = 0.f;
    for (int s = 0; s < S; s++) acc += Ps[l][s] * Vs[s][e];
    O[(b * 25 + l) * 512 + h * 64 + e] = acc;
  }
}

// ---------------- fused residual-add + LayerNorm (rows of 512) -----------
__global__ __launch_bounds__(128)
void add_ln(const float* __restrict__ a, const float* __restrict__ b,
            const float* __restrict__ gw, const float* __restrict__ bw,
            float* __restrict__ out) {
  const int row = blockIdx.x, t = threadIdx.x;
  float4 va = ((const float4*)(a + (size_t)row * 512))[t];
  float4 vb = ((const float4*)(b + (size_t)row * 512))[t];
  float4 v = make_float4(va.x + vb.x, va.y + vb.y, va.z + vb.z, va.w + vb.w);
  float s = v.x + v.y + v.z + v.w;
  float q = v.x * v.x + v.y * v.y + v.z * v.z + v.w * v.w;
#pragma unroll
  for (int off = 32; off > 0; off >>= 1) {
    s += __shfl_down(s, off);
    q += __shfl_down(q, off);
  }
  __shared__ float red[4];
  if ((t & 63) == 0) { red[(t >> 6) * 2] = s; red[(t >> 6) * 2 + 1] = q; }
  __syncthreads();
  float S_ = red[0] + red[2], Q_ = red[1] + red[3];
  float mean = S_ * (1.f / 512.f);
  float var  = Q_ * (1.f / 512.f) - mean * mean;
  float inv  = rsqrtf(var + EPS_LN);
  float4 g4 = ((const float4*)gw)[t];
  float4 b4 = ((const float4*)bw)[t];
  float4 o;
  o.x = (v.x - mean) * inv * g4.x + b4.x;
  o.y = (v.y - mean) * inv * g4.y + b4.y;
  o.z = (v.z - mean) * inv * g4.z + b4.z;
  o.w = (v.w - mean) * inv * g4.w + b4.w;
  ((float4*)(out + (size_t)row * 512))[t] = o;
}

// ---------------- transposes / LSTM preps --------------------------------
__global__ void transpose_dl(const float* __restrict__ in, float* __restrict__ outp) {
  const int b = blockIdx.x, t = threadIdx.x;
  for (int idx = t; idx < 25 * 512; idx += 256) {
    int l2 = idx / 512, c = idx % 512;
    outp[((size_t)b * 25 + l2) * 512 + c] = in[((size_t)b * 512 + c) * 25 + l2];
  }
}

// Wperm[l][112][64]: row r=4u+gate, k=0..24 -> Wih, k=32..56 -> Whh, else 0.
// gbias[l][112] = bih+bhh permuted (0 for pad units).
__global__ __launch_bounds__(256)
void prep_lstm_w(const float* __restrict__ Wih, const float* __restrict__ Whh,
                 const float* __restrict__ bih, const float* __restrict__ bhh,
                 _Float16* __restrict__ Wperm, float* __restrict__ gbias) {
  const int l = blockIdx.x, t = threadIdx.x;
  for (int idx = t; idx < 112 * 64; idx += 256) {
    int r = idx >> 6, k = idx & 63;
    int u = r >> 2, gi = r & 3;
    float v = 0.f;
    if (u < 25) {
      if (k < 25) v = Wih[((size_t)l * 100 + gi * 25 + u) * 25 + k];
      else if (k >= 32 && k < 57) v = Whh[((size_t)l * 100 + gi * 25 + u) * 25 + (k - 32)];
    }
    Wperm[(size_t)l * 7168 + idx] = (_Float16)v;
  }
  for (int idx = t; idx < 112; idx += 256) {
    int u = idx >> 2, gi = idx & 3;
    float v = 0.f;
    if (u < 25) v = bih[l * 100 + gi * 25 + u] + bhh[l * 100 + gi * 25 + u];
    gbias[l * 112 + idx] = v;
  }
}

// X0[t=512][b=128][32] f16 from x2[b][25][512] (u>=25 pads = 0)
__global__ __launch_bounds__(256)
void prep_x0(const float* __restrict__ x2, _Float16* __restrict__ X0) {
  __shared__ float tile[25][516];
  const int b = blockIdx.x, t = threadIdx.x;
  for (int idx = t; idx < 25 * 512; idx += 256) {
    int u = idx >> 9, d = idx & 511;
    tile[u][d] = x2[((size_t)b * 25 + u) * 512 + d];
  }
  __syncthreads();
  for (int idx = t; idx < 512 * 32; idx += 256) {
    int d = idx >> 5, u = idx & 31;
    X0[((size_t)d * 128 + b) * 32 + u] = (u < 25) ? (_Float16)tile[u][d] : (_Float16)0.f;
  }
}

// ---------------- MFMA persistent LSTM -----------------------------------
// 256 blocks x 64 threads: one wave per (layer l=bid>>3, group g=bid&7 of 16
// batches). Weight A-frags + bias C-frags + c-state in registers; h round-
// trips through 1KB LDS (write b16 scattered, read b128 = next-step B-frag
// AND the ring store value). Ring layout [slot][16b][32u] f16 = B-frag-ready;
// cross-block via relaxed agent atomics (MALL), flags after vmcnt(0) drain.
__device__ __forceinline__ int ld_rlx(int* p) {
  return __hip_atomic_load(p, __ATOMIC_RELAXED, __HIP_MEMORY_SCOPE_AGENT);
}
__device__ __forceinline__ void st_rlx(int* p, int v) {
  __hip_atomic_store(p, v, __ATOMIC_RELAXED, __HIP_MEMORY_SCOPE_AGENT);
}
__device__ __forceinline__ unsigned long long ldq_rlx(const unsigned long long* p) {
  return __hip_atomic_load(p, __ATOMIC_RELAXED, __HIP_MEMORY_SCOPE_AGENT);
}
__device__ __forceinline__ void stq_rlx(unsigned long long* p, unsigned long long v) {
  __hip_atomic_store(p, v, __ATOMIC_RELAXED, __HIP_MEMORY_SCOPE_AGENT);
}
__device__ __forceinline__ float tanh_fast(float x) {
  return 1.f - 2.f / (1.f + __expf(2.f * x));
}

__global__ __launch_bounds__(64) __attribute__((amdgpu_waves_per_eu(2, 2)))
void lstm_pipeline(const _Float16* __restrict__ X0, float* __restrict__ yout,
                   _Float16* __restrict__ ring, int* __restrict__ prod,
                   int* __restrict__ cons,
                   const _Float16* __restrict__ Wperm, const float* __restrict__ gbias) {
  const int l    = blockIdx.x >> 3;
  const int g    = blockIdx.x & 7;
  const int lane = threadIdx.x;
  const int col  = lane & 15;          // batch-in-group (MFMA n / C col)
  const int q8   = lane >> 4;          // k-quad (B) == row-quad (C/D)

  __shared__ _Float16 hbuf[16][40];    // [batch][unit], rows 80B (16B-aligned)

  // ---- A-frags: A[m=lane&15][k=quad*8+j]; 7 m-tiles x 2 k-halves --------
  h8v afr[7][2];
  f4v bias4[7];
  const _Float16* wp = Wperm + (size_t)l * 7168;
#pragma unroll
  for (int mt = 0; mt < 7; mt++) {
#pragma unroll
    for (int kh = 0; kh < 2; kh++)
      afr[mt][kh] = *(const h8v*)&wp[(mt * 16 + col) * 64 + kh * 32 + q8 * 8];
    bias4[mt] = *(const f4v*)&gbias[l * 112 + mt * 16 + q8 * 4];
  }
  float cst[7] = {0.f, 0.f, 0.f, 0.f, 0.f, 0.f, 0.f};
  h8v hv = {};                         // h B-frag (initial h = 0)
  for (int i = lane; i < 16 * 40; i += 64) (&hbuf[0][0])[i] = (_Float16)0.f;
  // single wave per block -> wave-coherent LDS, no barrier ever

  // ring region per (l,g): 64 slots x 16 b x 32 u halves = 8192 ull
  const unsigned long long* rin =
      (const unsigned long long*)(ring + ((size_t)((l > 0 ? l - 1 : 0) * 8 + g)) * 32768)
      + (size_t)col * 8 + q8 * 2;
  unsigned long long* rout =
      (unsigned long long*)(ring + ((size_t)(l * 8 + g)) * 32768)
      + (size_t)col * 8 + q8 * 2;
  int* pflag  = prod + ((l > 0 ? l - 1 : 0) * 8 + g);
  int* cflagn = cons + ((l < 31 ? l + 1 : 31) * 8 + g);
  const _Float16* x0base = X0 + ((size_t)(g * 16 + col)) * 32 + q8 * 8;

  for (int n = 0; n < 64; n++) {
    if (l > 0)            { while (ld_rlx(pflag)  < n + 1) __builtin_amdgcn_s_sleep(1); }
    if (l < 31 && n >= 8) { while (ld_rlx(cflagn) < n - 7) __builtin_amdgcn_s_sleep(1); }
    asm volatile("" ::: "memory");     // no hoisting loads above the poll

    // prefetch all 8 x-fragments of this chunk (16B each, coalesced 1KB/wave)
    unsigned long long xq0[8], xq1[8];
    if (l == 0) {
#pragma unroll
      for (int tc = 0; tc < 8; tc++) {
        const unsigned long long* p =
            (const unsigned long long*)(x0base + (size_t)(n * 8 + tc) * 128 * 32);
        xq0[tc] = p[0]; xq1[tc] = p[1];
      }
    } else {
      const unsigned long long* base = rin + (size_t)(n & 7) * 8 * 128;
#pragma unroll
      for (int tc = 0; tc < 8; tc++) {
        xq0[tc] = ldq_rlx(base + tc * 128);
        xq1[tc] = ldq_rlx(base + tc * 128 + 1);
      }
    }

#pragma unroll
    for (int tc = 0; tc < 8; tc++) {
      uint4 xi = make_uint4((unsigned)xq0[tc], (unsigned)(xq0[tc] >> 32),
                            (unsigned)xq1[tc], (unsigned)(xq1[tc] >> 32));
      h8v xv = __builtin_bit_cast(h8v, xi);
      f4v acc[7];
#pragma unroll
      for (int mt = 0; mt < 7; mt++) acc[mt] = bias4[mt];
#pragma unroll
      for (int mt = 0; mt < 7; mt++)
        acc[mt] = __builtin_amdgcn_mfma_f32_16x16x32_f16(afr[mt][0], xv, acc[mt], 0, 0, 0);
#pragma unroll
      for (int mt = 0; mt < 7; mt++)
        acc[mt] = __builtin_amdgcn_mfma_f32_16x16x32_f16(afr[mt][1], hv, acc[mt], 0, 0, 0);
      // elementwise: lane-local — unit u=mt*4+q8, batch=col, gates in regs
#pragma unroll
      for (int mt = 0; mt < 7; mt++) {
        const int u = mt * 4 + q8;
        float si = 1.f / (1.f + __expf(-acc[mt][0]));
        float sf = 1.f / (1.f + __expf(-acc[mt][1]));
        float so = 1.f / (1.f + __expf(-acc[mt][3]));
        float c  = sf * cst[mt] + si * tanh_fast(acc[mt][2]);
        cst[mt] = c;
        float h = so * tanh_fast(c);
        if (u < 25) {
          hbuf[col][u] = (_Float16)h;
          if (l == 31)
            yout[((size_t)(g * 16 + col) * 512 + (n * 8 + tc)) * 25 + u] = h;
        }
      }
      hv = *(const h8v*)&hbuf[col][q8 * 8];   // next-step B-frag == ring value
      if (l < 31) {
        uint4 hb = __builtin_bit_cast(uint4, hv);
        unsigned long long* rp = rout + ((size_t)((n & 7) * 8 + tc)) * 128;
        stq_rlx(rp,     (unsigned long long)hb.x | ((unsigned long long)hb.y << 32));
        stq_rlx(rp + 1, (unsigned long long)hb.z | ((unsigned long long)hb.w << 32));
      }
    }
    asm volatile("s_waitcnt vmcnt(0)" ::: "memory");  // stores at MALL
    if (lane == 0) {
      if (l < 31) st_rlx(&prod[l * 8 + g], n + 1);
      if (l > 0)  st_rlx(&cons[l * 8 + g], n + 1);
    }
  }
}

// =====================================================================
extern "C" void kernel_launch(void* const* d_in, const int* in_sizes, int n_in,
                              void* d_out, int out_size, void* d_ws, size_t ws_size,
                              hipStream_t stream) {
  const float* x     = (const float*)d_in[0];
  const float* cross = (const float*)d_in[1];
  const float* Wq_s = (const float*)d_in[2];  const float* bq_s = (const float*)d_in[3];
  const float* Wk_s = (const float*)d_in[4];  const float* bk_s = (const float*)d_in[5];
  const float* Wv_s = (const float*)d_in[6];  const float* bv_s = (const float*)d_in[7];
  const float* Wo_s = (const float*)d_in[8];  const float* bo_s = (const float*)d_in[9];
  const float* Wq_c = (const float*)d_in[10]; const float* bq_c = (const float*)d_in[11];
  const float* Wk_c = (const float*)d_in[12]; const float* bk_c = (const float*)d_in[13];
  const float* Wv_c = (const float*)d_in[14]; const float* bv_c = (const float*)d_in[15];
  const float* Wo_c = (const float*)d_in[16]; const float* bo_c = (const float*)d_in[17];
  const float* g1 = (const float*)d_in[18]; const float* b1 = (const float*)d_in[19];
  const float* g2 = (const float*)d_in[20]; const float* b2 = (const float*)d_in[21];
  const float* g3 = (const float*)d_in[22]; const float* b3 = (const float*)d_in[23];
  const float* Wih = (const float*)d_in[24];
  const float* Whh = (const float*)d_in[25];
  const float* bih = (const float*)d_in[26];
  const float* bhh = (const float*)d_in[27];
  const float* Wc  = (const float*)d_in[28]; const float* bc = (const float*)d_in[29];
  float* out = (float*)d_out;
  float* ws  = (float*)d_ws;

  // ---- workspace (floats); time-multiplexed (R5 map + LSTM arenas) ------
  constexpr size_t A  = 1638400;    // 3200*512
  constexpr size_t C6 = 6291456;    // 12288*512
  float* x1    = ws;
  float* Qc    = ws + A;
  // self phase
  float* Qs    = ws + 2 * A;
  float* Ks    = ws + 3 * A;
  float* Vs    = ws + 4 * A;
  float* attns = ws + 5 * A;
  float* tmp   = ws + 6 * A;
  float* Ps    = ws + 7 * A;
  // cross phase
  float* Kc    = ws + 2 * A;
  float* Vc    = ws + 2 * A + C6;
  float* attnc = ws + 2 * A + 2 * C6;
  float* Pc    = attnc + A;
  float* tmp2  = ws + 6 * A;
  float* x2    = ws + 3 * A;
  // lstm / post (all written AFTER cross phase -> may overlay Kc/Vc/tmp2)
  _Float16* X0b  = (_Float16*)(ws + 4 * A);      // 2,097,152 halves
  float*    youtb = ws + 5 * A;                  // [128][512][25] fp32
  _Float16* ringb = (_Float16*)(ws + 6 * A);     // 8,388,608 halves (16.8MB)
  _Float16* WpermB = (_Float16*)(ws + 14100000); // 229,376 halves
  float*    gbiasB = ws + 14300000;              // 3,584 floats
  float* ytb   = ws + 2 * A;
  float* fy    = ws + 5 * A;                     // after youtb dead
  _Float16* WTall = (_Float16*)(ws + 20000000);
  int* ctr = (int*)(ws + 21179648);

  dim3 blk(256);
  WPtrs wpq;
  wpq.p[0] = Wq_s; wpq.p[1] = Wk_s; wpq.p[2] = Wv_s; wpq.p[3] = Wo_s;
  wpq.p[4] = Wq_c; wpq.p[5] = Wk_c; wpq.p[6] = Wv_c; wpq.p[7] = Wo_c;
  wpq.p[8] = Wc;
  prep_weights<<<dim3(16, 16, 9), blk, 0, stream>>>(wpq, WTall);
  hipMemsetAsync(ctr, 0, 1024 * sizeof(int), stream);
  _Float16* WT[9];
  for (int i = 0; i < 9; i++) WT[i] = WTall + (size_t)i * 262144;

  // ---- self attention ----
  gemm3<<<dim3(24, 50), blk, 0, stream>>>(x, WT[0], WT[1], WT[2],
                                          bq_s, bk_s, bv_s, Qs, Ks, Vs, 3200);
  attn_scores<25><<<dim3(8, 128), blk, 0, stream>>>(Qs, Ks, Ps);
  attn_out<25><<<dim3(8, 128), blk, 0, stream>>>(Ps, Vs, attns);
  gemm3<<<dim3(8, 50), blk, 0, stream>>>(attns, WT[3], WT[3], WT[3],
                                         bo_s, bo_s, bo_s, tmp, tmp, tmp, 3200);
  add_ln<<<3200, 128, 0, stream>>>(x, tmp, g1, b1, x1);
  // ---- cross attention ----
  gemm3<<<dim3(8, 50), blk, 0, stream>>>(x1, WT[4], WT[4], WT[4],
                                         bq_c, bq_c, bq_c, Qc, Qc, Qc, 3200);
  gemm3<<<dim3(16, 192), blk, 0, stream>>>(cross, WT[5], WT[6], WT[6],
                                           bk_c, bv_c, bv_c, Kc, Vc, Vc, 12288);
  attn_scores<96><<<dim3(8, 128), blk, 0, stream>>>(Qc, Kc, Pc);
  attn_out<96><<<dim3(8, 128), blk, 0, stream>>>(Pc, Vc, attnc);
  gemm3<<<dim3(8, 50), blk, 0, stream>>>(attnc, WT[7], WT[7], WT[7],
                                         bo_c, bo_c, bo_c, tmp2, tmp2, tmp2, 3200);
  add_ln<<<3200, 128, 0, stream>>>(x1, tmp2, g2, b2, x2);
  // ---- LSTM over feature axis (persistent MFMA pipeline) ----
  prep_lstm_w<<<32, 256, 0, stream>>>(Wih, Whh, bih, bhh, WpermB, gbiasB);
  prep_x0<<<128, 256, 0, stream>>>(x2, X0b);
  lstm_pipeline<<<256, 64, 0, stream>>>(X0b, youtb, ringb, ctr, ctr + 256,
                                        WpermB, gbiasB);
  // ---- pointwise conv over channels + final LN ----
  transpose_dl<<<128, 256, 0, stream>>>(youtb, ytb);
  gemm3<<<dim3(8, 50), blk, 0, stream>>>(ytb, WT[8], WT[8], WT[8],
                                         bc, bc, bc, fy, fy, fy, 3200);
  add_ln<<<3200, 128, 0, stream>>>(x2, fy, g3, b3, out);
}